// Round 8
// baseline (349.975 us; speedup 1.0000x reference)
//
#include <hip/hip_runtime.h>
#include <hip/hip_cooperative_groups.h>

namespace cg = cooperative_groups;

// Problem constants
constexpr int Bn = 16, Cd = 256, Hn = 64, Wn = 64, Kc = 1024;
constexpr int QUANT_ELEMS = Bn * Hn * Wn * Cd;   // 16777216
constexpr int LOSS_OFF = QUANT_ELEMS;            // +0 codebook_loss, +1 commitment_loss
constexpr int IDX_OFF = QUANT_ELEMS + 2;         // 65536 indices (stored as float)

typedef _Float16 half8 __attribute__((ext_vector_type(8)));
typedef float f32x4 __attribute__((ext_vector_type(4)));

// ws layout (bytes):
constexpr size_t WS_CBFH = 0;                    // 512 KB fp16 hi codebook (B-frag)
constexpr size_t WS_CBFL = 512 * 1024;           // 512 KB fp16 lo residual
constexpr size_t WS_C2   = 1024 * 1024;          // 4 KB

// Gap threshold for exact full rescan (3-term error sigma ~1e-5).
constexpr float THR = 1e-4f;

static __device__ __forceinline__ float med3f(float a, float b, float c) {
#if __has_builtin(__builtin_amdgcn_fmed3f)
    return __builtin_amdgcn_fmed3f(a, b, c);
#else
    return fmaxf(fminf(a, b), fminf(fmaxf(a, b), c));
#endif
}

// ---------------------------------------------------------------------------
// FUSED cooperative kernel v12. Grid = 512 blocks x 512 threads = exactly the
// co-residency capacity (2 blocks/CU: LDS 2x70656 <= 160K, VGPR <= 64).
// Phase 1: distributed fragment prep (1 (ntile,kblk) unit per block) + c2.
// grid.sync(). Phase 2: v11 body for 2 consecutive bh tiles per block.
__global__ __launch_bounds__(512, 4) void vq_fused(const float* __restrict__ x,
                                                   const float* __restrict__ cb,
                                                   _Float16* __restrict__ cbFh,
                                                   _Float16* __restrict__ cbFl,
                                                   float* __restrict__ c2,
                                                   float* __restrict__ out) {
    __shared__ half8 Axh[2048];   // 32 KB: [kblk 8][mt 4][lane 64]
    __shared__ half8 Axl[2048];   // 32 KB
    __shared__ float q1ds[8][32];
    __shared__ int   q1is[8][32];
    __shared__ float q2ds[8][32];
    __shared__ int   idx_s[64];
    __shared__ float red[8];
    __shared__ int   flg[64];     // flagged row ids
    __shared__ int   nflag;
    __shared__ float scan_xs[256];   // exact x row for full rescan
    __shared__ float scan_d[8];
    __shared__ int   scan_k[8];

    const int tid = threadIdx.x;
    const int lane = tid & 63;
    const int wv = tid >> 6;          // 0..7
    const int mth = wv & 1;           // m-half: rows [mth*32, mth*32+32)
    const int ntq = wv >> 1;          // n-quarter: ntiles [ntq*16, ntq*16+16)

    // ================= Phase 1: fragment prep (one unit per block) ==========
    {
        const int unit = blockIdx.x;          // 512 units = 64 ntiles x 8 kblk
        const int ntile = unit >> 3, kblk = unit & 7;
        const int code_r = tid >> 5;          // 0..15
        const int cc = tid & 31;              // 0..31 (c within kblk slice)
        const float v = cb[(size_t)(ntile * 16 + code_r) * Cd + kblk * 32 + cc];
        const _Float16 hh = (_Float16)v;
        const _Float16 ll = (_Float16)(v - (float)hh);
        const int l = ((cc >> 3) << 4) | code_r;   // lane within fragment
        const int j = cc & 7;
        const size_t e = (size_t)(ntile * 8 + kblk) * 64 + l;
        cbFh[e * 8 + j] = hh;
        cbFl[e * 8 + j] = ll;
        if (kblk == 0) {   // c2 for this ntile's 16 codes (32 parts x 8 c)
            const int i = tid >> 5, part = tid & 31;
            const float* row = cb + (size_t)(ntile * 16 + i) * Cd;
            float s = 0.f;
            #pragma unroll
            for (int c0 = 0; c0 < 8; ++c0) { const float vv = row[part * 8 + c0]; s += vv * vv; }
            s += __shfl_xor(s, 1);
            s += __shfl_xor(s, 2);
            s += __shfl_xor(s, 4);
            s += __shfl_xor(s, 8);
            s += __shfl_xor(s, 16);
            if (part == 0) c2[ntile * 16 + i] = s;
        }
        if (unit == 0 && tid == 0) { out[LOSS_OFF] = 0.f; out[LOSS_OFF + 1] = 0.f; }
    }
    __threadfence();          // device-scope visibility across XCDs
    cg::this_grid().sync();

    // ================= Phase 2: two bh tiles per block ======================
    #pragma unroll 1
    for (int tt = 0; tt < 2; ++tt) {
        const int bh = blockIdx.x * 2 + tt;
        const int b = bh >> 6, h = bh & 63;

        if (tid == 0) nflag = 0;

        // ---- Stage x-tile: gather + fp16 hi/lo split + lane-contiguous writes
        {
            const int m = tid & 15;           // row within m-tile
            const int q = (tid >> 4) & 3;     // k-quad
            const int mtg = (tid >> 6) & 3;   // m-tile
            const int kh = tid >> 8;          // kblk-half (0/1)
            const int w = mtg * 16 + m;
            const float* xb = x + ((size_t)b * Cd * Hn + h) * Wn + w;   // + c*4096
            #pragma unroll
            for (int kk = 0; kk < 4; ++kk) {
                const int kblk = kh * 4 + kk;
                half8 hv, lv;
                #pragma unroll
                for (int j = 0; j < 8; ++j) {
                    const int c = kblk * 32 + q * 8 + j;
                    const float v = xb[(size_t)c * (Hn * Wn)];
                    const _Float16 hh = (_Float16)v;
                    hv[j] = hh;
                    lv[j] = (_Float16)(v - (float)hh);
                }
                const int e = (kblk * 4 + mtg) * 64 + (q * 16 + m);   // == ...*64 + lane
                Axh[e] = hv;
                Axl[e] = lv;
            }
        }
        __syncthreads();

        float q1d[8], q2d[8];
        int   q1i[8];
        #pragma unroll
        for (int i = 0; i < 8; ++i) { q1d[i] = 3.4e38f; q2d[i] = 3.4e38f; q1i[i] = 0; }

        // B-fragment prefetch slots (1-deep software pipeline)
        half8 nbh[2], nbl[2];
        #pragma unroll
        for (int nt = 0; nt < 2; ++nt) {
            const int ntile = ntq * 16 + nt;
            const size_t be = ((size_t)(ntile * 8) * 64 + lane) * 8;
            nbh[nt] = *(const half8*)(cbFh + be);
            nbl[nt] = *(const half8*)(cbFl + be);
        }

        #pragma unroll 1
        for (int grp = 0; grp < 8; ++grp) {   // 2 n-tiles per group
            f32x4 acc[2][2];   // [ml][nt]
            acc[0][0] = (f32x4){0.f, 0.f, 0.f, 0.f};
            acc[0][1] = (f32x4){0.f, 0.f, 0.f, 0.f};
            acc[1][0] = (f32x4){0.f, 0.f, 0.f, 0.f};
            acc[1][1] = (f32x4){0.f, 0.f, 0.f, 0.f};

            #pragma unroll 2
            for (int kblk = 0; kblk < 8; ++kblk) {
                // consume current slot
                const half8 cbh0 = nbh[0], cbh1 = nbh[1];
                const half8 cbl0 = nbl[0], cbl1 = nbl[1];
                // issue next-iteration loads (wraps harmlessly at the very end)
                {
                    const int nk = (kblk + 1) & 7;
                    const int ng = (grp + ((kblk + 1) >> 3)) & 7;
                    #pragma unroll
                    for (int nt = 0; nt < 2; ++nt) {
                        const int ntile = ntq * 16 + ng * 2 + nt;
                        const size_t be = ((size_t)(ntile * 8 + nk) * 64 + lane) * 8;
                        nbh[nt] = *(const half8*)(cbFh + be);
                        nbl[nt] = *(const half8*)(cbFl + be);
                    }
                }
                half8 ahf[2], alf[2];
                #pragma unroll
                for (int ml = 0; ml < 2; ++ml) {
                    const int e = (kblk * 4 + mth * 2 + ml) * 64 + lane;
                    ahf[ml] = Axh[e];
                    alf[ml] = Axl[e];
                }
                // 3 terms: xh*ch + xh*cl + xl*ch  (= x*c minus tiny xl*cl)
                __builtin_amdgcn_s_setprio(1);
                #pragma unroll
                for (int ml = 0; ml < 2; ++ml) {
                    acc[ml][0] = __builtin_amdgcn_mfma_f32_16x16x32_f16(ahf[ml], cbh0, acc[ml][0], 0, 0, 0);
                    acc[ml][1] = __builtin_amdgcn_mfma_f32_16x16x32_f16(ahf[ml], cbh1, acc[ml][1], 0, 0, 0);
                }
                #pragma unroll
                for (int ml = 0; ml < 2; ++ml) {
                    acc[ml][0] = __builtin_amdgcn_mfma_f32_16x16x32_f16(ahf[ml], cbl0, acc[ml][0], 0, 0, 0);
                    acc[ml][1] = __builtin_amdgcn_mfma_f32_16x16x32_f16(ahf[ml], cbl1, acc[ml][1], 0, 0, 0);
                }
                #pragma unroll
                for (int ml = 0; ml < 2; ++ml) {
                    acc[ml][0] = __builtin_amdgcn_mfma_f32_16x16x32_f16(alf[ml], cbh0, acc[ml][0], 0, 0, 0);
                    acc[ml][1] = __builtin_amdgcn_mfma_f32_16x16x32_f16(alf[ml], cbh1, acc[ml][1], 0, 0, 0);
                }
                __builtin_amdgcn_s_setprio(0);
            }

            // fold this group's 32 codes into per-row top-2 (lean: med3, no q2i)
            #pragma unroll
            for (int nt = 0; nt < 2; ++nt) {
                const int code = (ntq * 16 + grp * 2 + nt) * 16 + (lane & 15);
                const float c2v = c2[code];
                #pragma unroll
                for (int ml = 0; ml < 2; ++ml) {
                    #pragma unroll
                    for (int reg = 0; reg < 4; ++reg) {
                        const float d = fmaf(-2.f, acc[ml][nt][reg], c2v);
                        const int qi = ml * 4 + reg;
                        q2d[qi] = med3f(q1d[qi], q2d[qi], d);
                        q1i[qi] = (d < q1d[qi]) ? code : q1i[qi];
                        q1d[qi] = fminf(q1d[qi], d);
                    }
                }
            }
        }

        // cross-lane top-2 merge over the 16 code-columns (lane&15)
        #pragma unroll
        for (int off = 1; off < 16; off <<= 1) {
            #pragma unroll
            for (int qi = 0; qi < 8; ++qi) {
                const float od1 = __shfl_xor(q1d[qi], off);
                const int   oi1 = __shfl_xor(q1i[qi], off);
                const float od2 = __shfl_xor(q2d[qi], off);
                const float hi = fmaxf(q1d[qi], od1);
                q2d[qi] = fminf(fminf(q2d[qi], od2), hi);
                q1i[qi] = (od1 < q1d[qi]) ? oi1 : q1i[qi];
                q1d[qi] = fminf(q1d[qi], od1);
            }
        }
        if ((lane & 15) == 0) {
            #pragma unroll
            for (int qi = 0; qi < 8; ++qi) {
                const int ml = qi >> 2, reg = qi & 3;
                const int rl = ml * 16 + (lane >> 4) * 4 + reg;   // row within half (0..31)
                q1ds[wv][rl] = q1d[qi];
                q1is[wv][rl] = q1i[qi];
                q2ds[wv][rl] = q2d[qi];
            }
        }
        __syncthreads();
        if (tid < 64) {
            // row tid: half hh covered by waves {hh, hh+2, hh+4, hh+6}
            const int hh = tid >> 5, rl = tid & 31;
            float d1 = q1ds[hh][rl]; int i1 = q1is[hh][rl]; float d2 = q2ds[hh][rl];
            #pragma unroll
            for (int v = 1; v < 4; ++v) {
                const int w2 = hh + 2 * v;
                const float od1 = q1ds[w2][rl]; const int oi1 = q1is[w2][rl];
                const float od2 = q2ds[w2][rl];
                const float hi = fmaxf(d1, od1);
                d2 = fminf(fminf(d2, od2), hi);
                i1 = (od1 < d1) ? oi1 : i1;
                d1 = fminf(d1, od1);
            }
            idx_s[tid] = i1;
            if (d2 - d1 < THR) {                 // tight gap -> exact full rescan
                const int pos = atomicAdd(&nflag, 1);
                flg[pos] = tid;
            }
        }
        __syncthreads();

        // ---- Exact full 1024-code rescan of flagged rows (expected ~0).
        const int nf = nflag;
        for (int fi = 0; fi < nf; ++fi) {
            const int wrow = flg[fi];
            if (tid < 256) {
                const int c = tid;
                const int mt = wrow >> 4, m = wrow & 15;
                const int e = ((c >> 5) * 4 + mt) * 64 + ((c >> 3) & 3) * 16 + m;
                const int j = c & 7;
                scan_xs[c] = (float)Axh[e][j] + (float)Axl[e][j];
            }
            __syncthreads();
            float bd = 3.4e38f; int bk = 0;
            #pragma unroll
            for (int r = 0; r < 2; ++r) {
                const int code = tid * 2 + r;
                const float4* cr = (const float4*)(cb + (size_t)code * Cd);
                const float4* xr = (const float4*)scan_xs;
                float dot = 0.f;
                #pragma unroll 8
                for (int i = 0; i < 64; ++i) {
                    const float4 v = cr[i];
                    const float4 xv = xr[i];
                    dot = fmaf(v.x, xv.x, dot);
                    dot = fmaf(v.y, xv.y, dot);
                    dot = fmaf(v.z, xv.z, dot);
                    dot = fmaf(v.w, xv.w, dot);
                }
                const float d = c2[code] - 2.f * dot;
                if (d < bd || (d == bd && code < bk)) { bd = d; bk = code; }
            }
            #pragma unroll
            for (int off = 32; off >= 1; off >>= 1) {
                const float od = __shfl_xor(bd, off);
                const int   ok = __shfl_xor(bk, off);
                if (od < bd || (od == bd && ok < bk)) { bd = od; bk = ok; }
            }
            if (lane == 0) { scan_d[wv] = bd; scan_k[wv] = bk; }
            __syncthreads();
            if (tid == 0) {
                float fd = scan_d[0]; int fk = scan_k[0];
                #pragma unroll
                for (int v = 1; v < 8; ++v) {
                    const float od = scan_d[v]; const int ok = scan_k[v];
                    if (od < fd || (od == fd && ok < fk)) { fd = od; fk = ok; }
                }
                idx_s[wrow] = fk;
            }
            __syncthreads();
        }

        // indices out (post-rescan)
        if (tid < 64) out[IDX_OFF + bh * 64 + tid] = (float)idx_s[tid];

        // ---- Fused epilogue: quant gather, coalesced writes, loss from LDS-x.
        {
            const int w = tid & 63;           // row
            const int kblk = wv;              // c-eighth: c in [wv*32, wv*32+32)
            const int m = w & 15, mt = w >> 4;
            const int myidx = idx_s[w];
            const float4* cbrow = (const float4*)(cb + (size_t)myidx * Cd + kblk * 32);
            float lsum = 0.f;
            #pragma unroll
            for (int q = 0; q < 4; ++q) {
                const int e = (kblk * 4 + mt) * 64 + q * 16 + m;
                const half8 hv = Axh[e];
                const half8 lv = Axl[e];
                const float4 qa = cbrow[q * 2];
                const float4 qb = cbrow[q * 2 + 1];
                const float qv[8] = {qa.x, qa.y, qa.z, qa.w, qb.x, qb.y, qb.z, qb.w};
                const int cbase = kblk * 32 + q * 8;
                #pragma unroll
                for (int j = 0; j < 8; ++j) {
                    const float xv = (float)hv[j] + (float)lv[j];
                    const float dd = qv[j] - xv;
                    lsum += dd * dd;
                    out[(((size_t)b * Cd + cbase + j) * Hn + h) * Wn + w] = qv[j];
                }
            }
            #pragma unroll
            for (int off = 32; off >= 1; off >>= 1) lsum += __shfl_xor(lsum, off);
            if (lane == 0) red[wv] = lsum;
        }
        __syncthreads();
        if (tid == 0) {
            float s = 0.f;
            #pragma unroll
            for (int i = 0; i < 8; ++i) s += red[i];
            s *= (1.0f / 16777216.0f);
            atomicAdd(out + LOSS_OFF, s);
            atomicAdd(out + LOSS_OFF + 1, s);
        }
    }
}

// ---------------------------------------------------------------------------
// Fallback path (two classic launches) in case cooperative launch fails.
__global__ __launch_bounds__(256) void prep(const float* __restrict__ cb,
                                            _Float16* __restrict__ cbFh,
                                            _Float16* __restrict__ cbFl,
                                            float* __restrict__ c2,
                                            float* __restrict__ out) {
    __shared__ float cbs[16][257];
    const int tid = threadIdx.x;
    const int k0 = blockIdx.x * 16;
    {
        const int c4 = (tid & 63) * 4;
        const int r0 = tid >> 6;
        #pragma unroll
        for (int it = 0; it < 4; ++it) {
            const int r = r0 + it * 4;
            const float4 v = *(const float4*)&cb[(size_t)(k0 + r) * Cd + c4];
            cbs[r][c4] = v.x; cbs[r][c4 + 1] = v.y; cbs[r][c4 + 2] = v.z; cbs[r][c4 + 3] = v.w;
        }
    }
    __syncthreads();
    {
        const int i = tid >> 4, part = tid & 15;
        float s = 0.f;
        #pragma unroll
        for (int c = part * 16; c < part * 16 + 16; ++c) { const float v = cbs[i][c]; s += v * v; }
        s += __shfl_xor(s, 1);
        s += __shfl_xor(s, 2);
        s += __shfl_xor(s, 4);
        s += __shfl_xor(s, 8);
        if (part == 0) c2[k0 + i] = s;
    }
    for (int t = tid; t < 512; t += 256) {
        const int kblk = t >> 6;
        const int l = t & 63;
        const int code_l = l & 15;
        const int cbase = kblk * 32 + (l >> 4) * 8;
        half8 hv, lv;
        #pragma unroll
        for (int j = 0; j < 8; ++j) {
            const float v = cbs[code_l][cbase + j];
            const _Float16 hh = (_Float16)v;
            hv[j] = hh;
            lv[j] = (_Float16)(v - (float)hh);
        }
        const size_t e = (size_t)(blockIdx.x * 8 + kblk) * 64 + l;
        *(half8*)(cbFh + e * 8) = hv;
        *(half8*)(cbFl + e * 8) = lv;
    }
    if (blockIdx.x == 0 && tid == 0) {
        out[LOSS_OFF] = 0.f; out[LOSS_OFF + 1] = 0.f;
    }
}

__global__ __launch_bounds__(512, 4) void vq_main_fb(const float* __restrict__ x,
                                                     const float* __restrict__ cb,
                                                     const _Float16* __restrict__ cbFh,
                                                     const _Float16* __restrict__ cbFl,
                                                     const float* __restrict__ c2,
                                                     float* __restrict__ out) {
    // Single-tile version of phase 2 (v11-equivalent), used only on fallback.
    __shared__ half8 Axh[2048];
    __shared__ half8 Axl[2048];
    __shared__ float q1ds[8][32];
    __shared__ int   q1is[8][32];
    __shared__ float q2ds[8][32];
    __shared__ int   idx_s[64];
    __shared__ float red[8];
    __shared__ int   flg[64];
    __shared__ int   nflag;
    __shared__ float scan_xs[256];
    __shared__ float scan_d[8];
    __shared__ int   scan_k[8];

    const int tid = threadIdx.x;
    const int lane = tid & 63;
    const int wv = tid >> 6;
    const int mth = wv & 1;
    const int ntq = wv >> 1;
    const int bh = blockIdx.x;
    const int b = bh >> 6, h = bh & 63;

    if (tid == 0) nflag = 0;
    {
        const int m = tid & 15;
        const int q = (tid >> 4) & 3;
        const int mtg = (tid >> 6) & 3;
        const int kh = tid >> 8;
        const int w = mtg * 16 + m;
        const float* xb = x + ((size_t)b * Cd * Hn + h) * Wn + w;
        #pragma unroll
        for (int kk = 0; kk < 4; ++kk) {
            const int kblk = kh * 4 + kk;
            half8 hv, lv;
            #pragma unroll
            for (int j = 0; j < 8; ++j) {
                const int c = kblk * 32 + q * 8 + j;
                const float v = xb[(size_t)c * (Hn * Wn)];
                const _Float16 hh = (_Float16)v;
                hv[j] = hh;
                lv[j] = (_Float16)(v - (float)hh);
            }
            const int e = (kblk * 4 + mtg) * 64 + (q * 16 + m);
            Axh[e] = hv;
            Axl[e] = lv;
        }
    }
    __syncthreads();

    float q1d[8], q2d[8];
    int   q1i[8];
    #pragma unroll
    for (int i = 0; i < 8; ++i) { q1d[i] = 3.4e38f; q2d[i] = 3.4e38f; q1i[i] = 0; }

    half8 nbh[2], nbl[2];
    #pragma unroll
    for (int nt = 0; nt < 2; ++nt) {
        const int ntile = ntq * 16 + nt;
        const size_t be = ((size_t)(ntile * 8) * 64 + lane) * 8;
        nbh[nt] = *(const half8*)(cbFh + be);
        nbl[nt] = *(const half8*)(cbFl + be);
    }

    #pragma unroll 1
    for (int grp = 0; grp < 8; ++grp) {
        f32x4 acc[2][2];
        acc[0][0] = (f32x4){0.f, 0.f, 0.f, 0.f};
        acc[0][1] = (f32x4){0.f, 0.f, 0.f, 0.f};
        acc[1][0] = (f32x4){0.f, 0.f, 0.f, 0.f};
        acc[1][1] = (f32x4){0.f, 0.f, 0.f, 0.f};

        #pragma unroll 2
        for (int kblk = 0; kblk < 8; ++kblk) {
            const half8 cbh0 = nbh[0], cbh1 = nbh[1];
            const half8 cbl0 = nbl[0], cbl1 = nbl[1];
            {
                const int nk = (kblk + 1) & 7;
                const int ng = (grp + ((kblk + 1) >> 3)) & 7;
                #pragma unroll
                for (int nt = 0; nt < 2; ++nt) {
                    const int ntile = ntq * 16 + ng * 2 + nt;
                    const size_t be = ((size_t)(ntile * 8 + nk) * 64 + lane) * 8;
                    nbh[nt] = *(const half8*)(cbFh + be);
                    nbl[nt] = *(const half8*)(cbFl + be);
                }
            }
            half8 ahf[2], alf[2];
            #pragma unroll
            for (int ml = 0; ml < 2; ++ml) {
                const int e = (kblk * 4 + mth * 2 + ml) * 64 + lane;
                ahf[ml] = Axh[e];
                alf[ml] = Axl[e];
            }
            __builtin_amdgcn_s_setprio(1);
            #pragma unroll
            for (int ml = 0; ml < 2; ++ml) {
                acc[ml][0] = __builtin_amdgcn_mfma_f32_16x16x32_f16(ahf[ml], cbh0, acc[ml][0], 0, 0, 0);
                acc[ml][1] = __builtin_amdgcn_mfma_f32_16x16x32_f16(ahf[ml], cbh1, acc[ml][1], 0, 0, 0);
            }
            #pragma unroll
            for (int ml = 0; ml < 2; ++ml) {
                acc[ml][0] = __builtin_amdgcn_mfma_f32_16x16x32_f16(ahf[ml], cbl0, acc[ml][0], 0, 0, 0);
                acc[ml][1] = __builtin_amdgcn_mfma_f32_16x16x32_f16(ahf[ml], cbl1, acc[ml][1], 0, 0, 0);
            }
            #pragma unroll
            for (int ml = 0; ml < 2; ++ml) {
                acc[ml][0] = __builtin_amdgcn_mfma_f32_16x16x32_f16(alf[ml], cbh0, acc[ml][0], 0, 0, 0);
                acc[ml][1] = __builtin_amdgcn_mfma_f32_16x16x32_f16(alf[ml], cbh1, acc[ml][1], 0, 0, 0);
            }
            __builtin_amdgcn_s_setprio(0);
        }

        #pragma unroll
        for (int nt = 0; nt < 2; ++nt) {
            const int code = (ntq * 16 + grp * 2 + nt) * 16 + (lane & 15);
            const float c2v = c2[code];
            #pragma unroll
            for (int ml = 0; ml < 2; ++ml) {
                #pragma unroll
                for (int reg = 0; reg < 4; ++reg) {
                    const float d = fmaf(-2.f, acc[ml][nt][reg], c2v);
                    const int qi = ml * 4 + reg;
                    q2d[qi] = med3f(q1d[qi], q2d[qi], d);
                    q1i[qi] = (d < q1d[qi]) ? code : q1i[qi];
                    q1d[qi] = fminf(q1d[qi], d);
                }
            }
        }
    }

    #pragma unroll
    for (int off = 1; off < 16; off <<= 1) {
        #pragma unroll
        for (int qi = 0; qi < 8; ++qi) {
            const float od1 = __shfl_xor(q1d[qi], off);
            const int   oi1 = __shfl_xor(q1i[qi], off);
            const float od2 = __shfl_xor(q2d[qi], off);
            const float hi = fmaxf(q1d[qi], od1);
            q2d[qi] = fminf(fminf(q2d[qi], od2), hi);
            q1i[qi] = (od1 < q1d[qi]) ? oi1 : q1i[qi];
            q1d[qi] = fminf(q1d[qi], od1);
        }
    }
    if ((lane & 15) == 0) {
        #pragma unroll
        for (int qi = 0; qi < 8; ++qi) {
            const int ml = qi >> 2, reg = qi & 3;
            const int rl = ml * 16 + (lane >> 4) * 4 + reg;
            q1ds[wv][rl] = q1d[qi];
            q1is[wv][rl] = q1i[qi];
            q2ds[wv][rl] = q2d[qi];
        }
    }
    __syncthreads();
    if (tid < 64) {
        const int hh = tid >> 5, rl = tid & 31;
        float d1 = q1ds[hh][rl]; int i1 = q1is[hh][rl]; float d2 = q2ds[hh][rl];
        #pragma unroll
        for (int v = 1; v < 4; ++v) {
            const int w2 = hh + 2 * v;
            const float od1 = q1ds[w2][rl]; const int oi1 = q1is[w2][rl];
            const float od2 = q2ds[w2][rl];
            const float hi = fmaxf(d1, od1);
            d2 = fminf(fminf(d2, od2), hi);
            i1 = (od1 < d1) ? oi1 : i1;
            d1 = fminf(d1, od1);
        }
        idx_s[tid] = i1;
        if (d2 - d1 < THR) {
            const int pos = atomicAdd(&nflag, 1);
            flg[pos] = tid;
        }
    }
    __syncthreads();

    const int nf = nflag;
    for (int fi = 0; fi < nf; ++fi) {
        const int wrow = flg[fi];
        if (tid < 256) {
            const int c = tid;
            const int mt = wrow >> 4, m = wrow & 15;
            const int e = ((c >> 5) * 4 + mt) * 64 + ((c >> 3) & 3) * 16 + m;
            const int j = c & 7;
            scan_xs[c] = (float)Axh[e][j] + (float)Axl[e][j];
        }
        __syncthreads();
        float bd = 3.4e38f; int bk = 0;
        #pragma unroll
        for (int r = 0; r < 2; ++r) {
            const int code = tid * 2 + r;
            const float4* cr = (const float4*)(cb + (size_t)code * Cd);
            const float4* xr = (const float4*)scan_xs;
            float dot = 0.f;
            #pragma unroll 8
            for (int i = 0; i < 64; ++i) {
                const float4 v = cr[i];
                const float4 xv = xr[i];
                dot = fmaf(v.x, xv.x, dot);
                dot = fmaf(v.y, xv.y, dot);
                dot = fmaf(v.z, xv.z, dot);
                dot = fmaf(v.w, xv.w, dot);
            }
            const float d = c2[code] - 2.f * dot;
            if (d < bd || (d == bd && code < bk)) { bd = d; bk = code; }
        }
        #pragma unroll
        for (int off = 32; off >= 1; off >>= 1) {
            const float od = __shfl_xor(bd, off);
            const int   ok = __shfl_xor(bk, off);
            if (od < bd || (od == bd && ok < bk)) { bd = od; bk = ok; }
        }
        if (lane == 0) { scan_d[wv] = bd; scan_k[wv] = bk; }
        __syncthreads();
        if (tid == 0) {
            float fd = scan_d[0]; int fk = scan_k[0];
            #pragma unroll
            for (int v = 1; v < 8; ++v) {
                const float od = scan_d[v]; const int ok = scan_k[v];
                if (od < fd || (od == fd && ok < fk)) { fd = od; fk = ok; }
            }
            idx_s[wrow] = fk;
        }
        __syncthreads();
    }

    if (tid < 64) out[IDX_OFF + bh * 64 + tid] = (float)idx_s[tid];

    {
        const int w = tid & 63;
        const int kblk = wv;
        const int m = w & 15, mt = w >> 4;
        const int myidx = idx_s[w];
        const float4* cbrow = (const float4*)(cb + (size_t)myidx * Cd + kblk * 32);
        float lsum = 0.f;
        #pragma unroll
        for (int q = 0; q < 4; ++q) {
            const int e = (kblk * 4 + mt) * 64 + q * 16 + m;
            const half8 hv = Axh[e];
            const half8 lv = Axl[e];
            const float4 qa = cbrow[q * 2];
            const float4 qb = cbrow[q * 2 + 1];
            const float qv[8] = {qa.x, qa.y, qa.z, qa.w, qb.x, qb.y, qb.z, qb.w};
            const int cbase = kblk * 32 + q * 8;
            #pragma unroll
            for (int j = 0; j < 8; ++j) {
                const float xv = (float)hv[j] + (float)lv[j];
                const float dd = qv[j] - xv;
                lsum += dd * dd;
                out[(((size_t)b * Cd + cbase + j) * Hn + h) * Wn + w] = qv[j];
            }
        }
        #pragma unroll
        for (int off = 32; off >= 1; off >>= 1) lsum += __shfl_xor(lsum, off);
        if (lane == 0) red[wv] = lsum;
    }
    __syncthreads();
    if (tid == 0) {
        float s = 0.f;
        #pragma unroll
        for (int i = 0; i < 8; ++i) s += red[i];
        s *= (1.0f / 16777216.0f);
        atomicAdd(out + LOSS_OFF, s);
        atomicAdd(out + LOSS_OFF + 1, s);
    }
}

// ---------------------------------------------------------------------------
extern "C" void kernel_launch(void* const* d_in, const int* in_sizes, int n_in,
                              void* d_out, int out_size, void* d_ws, size_t ws_size,
                              hipStream_t stream) {
    const float* x  = (const float*)d_in[0];   // (16,256,64,64)
    const float* cb = (const float*)d_in[1];   // (1024,256)
    float* out = (float*)d_out;
    char* ws = (char*)d_ws;
    _Float16* cbFh = (_Float16*)(ws + WS_CBFH);
    _Float16* cbFl = (_Float16*)(ws + WS_CBFL);
    float* c2      = (float*)(ws + WS_C2);

    void* args[] = {(void*)&x, (void*)&cb, (void*)&cbFh, (void*)&cbFl,
                    (void*)&c2, (void*)&out};
    const hipError_t err = hipLaunchCooperativeKernel(
        (const void*)vq_fused, dim3(512), dim3(512), args, 0, stream);
    if (err != hipSuccess) {
        // Fallback: classic two-kernel path (v11-equivalent).
        prep<<<64, 256, 0, stream>>>(cb, cbFh, cbFl, c2, out);
        vq_main_fb<<<Bn * Hn, 512, 0, stream>>>(x, cb, cbFh, cbFl, c2, out);
    }
}

// Round 9
// 213.054 us; speedup vs baseline: 1.6427x; 1.6427x over previous
//
#include <hip/hip_runtime.h>

// Problem constants
constexpr int Bn = 16, Cd = 256, Hn = 64, Wn = 64, Kc = 1024;
constexpr int QUANT_ELEMS = Bn * Hn * Wn * Cd;   // 16777216
constexpr int LOSS_OFF = QUANT_ELEMS;            // +0 codebook_loss, +1 commitment_loss
constexpr int IDX_OFF = QUANT_ELEMS + 2;         // 65536 indices (stored as float)

typedef _Float16 half8 __attribute__((ext_vector_type(8)));
typedef float f32x4 __attribute__((ext_vector_type(4)));

// ws layout (bytes):
constexpr size_t WS_CBFH = 0;                    // 512 KB fp16 hi codebook (B-frag)
constexpr size_t WS_CBFL = 512 * 1024;           // 512 KB fp16 lo residual
constexpr size_t WS_C2   = 1024 * 1024;          // 4 KB

// Gap threshold for exact full rescan (3-term error sigma ~1e-5).
constexpr float THR = 1e-4f;

static __device__ __forceinline__ float med3f(float a, float b, float c) {
#if __has_builtin(__builtin_amdgcn_fmed3f)
    return __builtin_amdgcn_fmed3f(a, b, c);
#else
    return fmaxf(fminf(a, b), fminf(fmaxf(a, b), c));
#endif
}

// ---------------------------------------------------------------------------
// Prep v13: 512 blocks, one (ntile,kblk) fragment unit each (this exact
// distribution was correctness-verified as v12's phase 1). c2 on kblk==0
// blocks. ~3 us vs ~8 us for the 64-block version.
__global__ __launch_bounds__(512) void prep(const float* __restrict__ cb,
                                            _Float16* __restrict__ cbFh,
                                            _Float16* __restrict__ cbFl,
                                            float* __restrict__ c2,
                                            float* __restrict__ out) {
    const int tid = threadIdx.x;
    const int unit = blockIdx.x;          // 512 units = 64 ntiles x 8 kblk
    const int ntile = unit >> 3, kblk = unit & 7;
    const int code_r = tid >> 5;          // 0..15
    const int cc = tid & 31;              // 0..31 (c within kblk slice)
    const float v = cb[(size_t)(ntile * 16 + code_r) * Cd + kblk * 32 + cc];
    const _Float16 hh = (_Float16)v;
    const _Float16 ll = (_Float16)(v - (float)hh);
    const int l = ((cc >> 3) << 4) | code_r;   // lane within fragment
    const int j = cc & 7;
    const size_t e = (size_t)(ntile * 8 + kblk) * 64 + l;
    cbFh[e * 8 + j] = hh;
    cbFl[e * 8 + j] = ll;
    if (kblk == 0) {   // c2 for this ntile's 16 codes (32 parts x 8 c)
        const int i = tid >> 5, part = tid & 31;
        const float* row = cb + (size_t)(ntile * 16 + i) * Cd;
        float s = 0.f;
        #pragma unroll
        for (int c0 = 0; c0 < 8; ++c0) { const float vv = row[part * 8 + c0]; s += vv * vv; }
        s += __shfl_xor(s, 1);
        s += __shfl_xor(s, 2);
        s += __shfl_xor(s, 4);
        s += __shfl_xor(s, 8);
        s += __shfl_xor(s, 16);
        if (part == 0) c2[ntile * 16 + i] = s;
    }
    if (unit == 0 && tid == 0) { out[LOSS_OFF] = 0.f; out[LOSS_OFF + 1] = 0.f; }
}

// ---------------------------------------------------------------------------
// Main MFMA kernel v13 = v11 (proven: VGPR 60, no scratch, 128 us) + one
// __syncthreads() per grp in the K-loop. Rationale: the mth-pair of waves
// (2q, 2q+1) read IDENTICAL B-fragment addresses; per-(grp,kblk) working set
// is 16 KB < 32 KB L1, so keeping the pair time-aligned turns the second
// read into an L1 hit -> B L2 traffic 2 GB -> ~1 GB (est. 58 -> 29 us wall).
// Waves drift without a barrier; 8 barriers/tile re-lockstep them.
__global__ __launch_bounds__(512, 4) void vq_main(const float* __restrict__ x,
                                                  const _Float16* __restrict__ cbFh,
                                                  const _Float16* __restrict__ cbFl,
                                                  const float* __restrict__ c2,
                                                  const float* __restrict__ cb,
                                                  float* __restrict__ out) {
    __shared__ half8 Axh[2048];   // 32 KB: [kblk 8][mt 4][lane 64]
    __shared__ half8 Axl[2048];   // 32 KB
    __shared__ float q1ds[8][32];
    __shared__ int   q1is[8][32];
    __shared__ float q2ds[8][32];
    __shared__ int   idx_s[64];
    __shared__ float red[8];
    __shared__ int   flg[64];     // flagged row ids
    __shared__ int   nflag;
    __shared__ float scan_xs[256];   // exact x row for full rescan
    __shared__ float scan_d[8];
    __shared__ int   scan_k[8];

    const int tid = threadIdx.x;
    const int lane = tid & 63;
    const int wv = tid >> 6;          // 0..7
    const int mth = wv & 1;           // m-half: rows [mth*32, mth*32+32)
    const int ntq = wv >> 1;          // n-quarter: ntiles [ntq*16, ntq*16+16)
    const int bh = blockIdx.x;
    const int b = bh >> 6, h = bh & 63;

    if (tid == 0) nflag = 0;

    // ---- Stage x-tile once: gather + fp16 hi/lo split + lane-contiguous writes
    {
        const int m = tid & 15;           // row within m-tile
        const int q = (tid >> 4) & 3;     // k-quad
        const int mtg = (tid >> 6) & 3;   // m-tile
        const int kh = tid >> 8;          // kblk-half (0/1)
        const int w = mtg * 16 + m;
        const float* xb = x + ((size_t)b * Cd * Hn + h) * Wn + w;   // + c*4096
        #pragma unroll
        for (int kk = 0; kk < 4; ++kk) {
            const int kblk = kh * 4 + kk;
            half8 hv, lv;
            #pragma unroll
            for (int j = 0; j < 8; ++j) {
                const int c = kblk * 32 + q * 8 + j;
                const float v = xb[(size_t)c * (Hn * Wn)];
                const _Float16 hh = (_Float16)v;
                hv[j] = hh;
                lv[j] = (_Float16)(v - (float)hh);
            }
            const int e = (kblk * 4 + mtg) * 64 + (q * 16 + m);   // == ...*64 + lane
            Axh[e] = hv;
            Axl[e] = lv;
        }
    }
    __syncthreads();

    float q1d[8], q2d[8];
    int   q1i[8];
    #pragma unroll
    for (int i = 0; i < 8; ++i) { q1d[i] = 3.4e38f; q2d[i] = 3.4e38f; q1i[i] = 0; }

    // B-fragment prefetch slots (1-deep software pipeline) — v8/v11-identical
    half8 nbh[2], nbl[2];
    #pragma unroll
    for (int nt = 0; nt < 2; ++nt) {
        const int ntile = ntq * 16 + nt;
        const size_t be = ((size_t)(ntile * 8) * 64 + lane) * 8;
        nbh[nt] = *(const half8*)(cbFh + be);
        nbl[nt] = *(const half8*)(cbFl + be);
    }

    #pragma unroll 1
    for (int grp = 0; grp < 8; ++grp) {   // 2 n-tiles per group
        // re-lockstep the 8 waves so mth-pairs share B through L1
        __syncthreads();

        f32x4 acc[2][2];   // [ml][nt]
        acc[0][0] = (f32x4){0.f, 0.f, 0.f, 0.f};
        acc[0][1] = (f32x4){0.f, 0.f, 0.f, 0.f};
        acc[1][0] = (f32x4){0.f, 0.f, 0.f, 0.f};
        acc[1][1] = (f32x4){0.f, 0.f, 0.f, 0.f};

        #pragma unroll 2
        for (int kblk = 0; kblk < 8; ++kblk) {
            // consume current slot
            const half8 cbh0 = nbh[0], cbh1 = nbh[1];
            const half8 cbl0 = nbl[0], cbl1 = nbl[1];
            // issue next-iteration loads (wraps harmlessly at the very end)
            {
                const int nk = (kblk + 1) & 7;
                const int ng = (grp + ((kblk + 1) >> 3)) & 7;
                #pragma unroll
                for (int nt = 0; nt < 2; ++nt) {
                    const int ntile = ntq * 16 + ng * 2 + nt;
                    const size_t be = ((size_t)(ntile * 8 + nk) * 64 + lane) * 8;
                    nbh[nt] = *(const half8*)(cbFh + be);
                    nbl[nt] = *(const half8*)(cbFl + be);
                }
            }
            half8 ahf[2], alf[2];
            #pragma unroll
            for (int ml = 0; ml < 2; ++ml) {
                const int e = (kblk * 4 + mth * 2 + ml) * 64 + lane;
                ahf[ml] = Axh[e];
                alf[ml] = Axl[e];
            }
            // 3 terms: xh*ch + xh*cl + xl*ch  (= x*c minus tiny xl*cl)
            __builtin_amdgcn_s_setprio(1);
            #pragma unroll
            for (int ml = 0; ml < 2; ++ml) {
                acc[ml][0] = __builtin_amdgcn_mfma_f32_16x16x32_f16(ahf[ml], cbh0, acc[ml][0], 0, 0, 0);
                acc[ml][1] = __builtin_amdgcn_mfma_f32_16x16x32_f16(ahf[ml], cbh1, acc[ml][1], 0, 0, 0);
            }
            #pragma unroll
            for (int ml = 0; ml < 2; ++ml) {
                acc[ml][0] = __builtin_amdgcn_mfma_f32_16x16x32_f16(ahf[ml], cbl0, acc[ml][0], 0, 0, 0);
                acc[ml][1] = __builtin_amdgcn_mfma_f32_16x16x32_f16(ahf[ml], cbl1, acc[ml][1], 0, 0, 0);
            }
            #pragma unroll
            for (int ml = 0; ml < 2; ++ml) {
                acc[ml][0] = __builtin_amdgcn_mfma_f32_16x16x32_f16(alf[ml], cbh0, acc[ml][0], 0, 0, 0);
                acc[ml][1] = __builtin_amdgcn_mfma_f32_16x16x32_f16(alf[ml], cbh1, acc[ml][1], 0, 0, 0);
            }
            __builtin_amdgcn_s_setprio(0);
        }

        // fold this group's 32 codes into per-row top-2 (lean: med3, no q2i)
        #pragma unroll
        for (int nt = 0; nt < 2; ++nt) {
            const int code = (ntq * 16 + grp * 2 + nt) * 16 + (lane & 15);
            const float c2v = c2[code];
            #pragma unroll
            for (int ml = 0; ml < 2; ++ml) {
                #pragma unroll
                for (int reg = 0; reg < 4; ++reg) {
                    const float d = fmaf(-2.f, acc[ml][nt][reg], c2v);
                    const int qi = ml * 4 + reg;
                    q2d[qi] = med3f(q1d[qi], q2d[qi], d);
                    q1i[qi] = (d < q1d[qi]) ? code : q1i[qi];
                    q1d[qi] = fminf(q1d[qi], d);
                }
            }
        }
    }

    // cross-lane top-2 merge over the 16 code-columns (lane&15)
    #pragma unroll
    for (int off = 1; off < 16; off <<= 1) {
        #pragma unroll
        for (int qi = 0; qi < 8; ++qi) {
            const float od1 = __shfl_xor(q1d[qi], off);
            const int   oi1 = __shfl_xor(q1i[qi], off);
            const float od2 = __shfl_xor(q2d[qi], off);
            const float hi = fmaxf(q1d[qi], od1);
            q2d[qi] = fminf(fminf(q2d[qi], od2), hi);
            q1i[qi] = (od1 < q1d[qi]) ? oi1 : q1i[qi];
            q1d[qi] = fminf(q1d[qi], od1);
        }
    }
    if ((lane & 15) == 0) {
        #pragma unroll
        for (int qi = 0; qi < 8; ++qi) {
            const int ml = qi >> 2, reg = qi & 3;
            const int rl = ml * 16 + (lane >> 4) * 4 + reg;   // row within half (0..31)
            q1ds[wv][rl] = q1d[qi];
            q1is[wv][rl] = q1i[qi];
            q2ds[wv][rl] = q2d[qi];
        }
    }
    __syncthreads();
    if (tid < 64) {
        // row tid: half hh covered by waves {hh, hh+2, hh+4, hh+6} (code-ascending)
        const int hh = tid >> 5, rl = tid & 31;
        float d1 = q1ds[hh][rl]; int i1 = q1is[hh][rl]; float d2 = q2ds[hh][rl];
        #pragma unroll
        for (int v = 1; v < 4; ++v) {
            const int w2 = hh + 2 * v;
            const float od1 = q1ds[w2][rl]; const int oi1 = q1is[w2][rl];
            const float od2 = q2ds[w2][rl];
            const float hi = fmaxf(d1, od1);
            d2 = fminf(fminf(d2, od2), hi);
            i1 = (od1 < d1) ? oi1 : i1;
            d1 = fminf(d1, od1);
        }
        idx_s[tid] = i1;
        if (d2 - d1 < THR) {                 // tight gap -> exact full rescan
            const int pos = atomicAdd(&nflag, 1);
            flg[pos] = tid;
        }
    }
    __syncthreads();

    // ---- Exact full 1024-code rescan of flagged rows (expected ~0 per block).
    // Exact x from LDS (xh+xl, err ~2^-24); d = c2 - 2*dot fp32; tie -> lowest k.
    const int nf = nflag;
    for (int fi = 0; fi < nf; ++fi) {
        const int wrow = flg[fi];
        if (tid < 256) {
            const int c = tid;
            const int mt = wrow >> 4, m = wrow & 15;
            const int e = ((c >> 5) * 4 + mt) * 64 + ((c >> 3) & 3) * 16 + m;
            const int j = c & 7;
            scan_xs[c] = (float)Axh[e][j] + (float)Axl[e][j];
        }
        __syncthreads();
        float bd = 3.4e38f; int bk = 0;
        #pragma unroll
        for (int r = 0; r < 2; ++r) {
            const int code = tid * 2 + r;
            const float4* cr = (const float4*)(cb + (size_t)code * Cd);
            const float4* xr = (const float4*)scan_xs;
            float dot = 0.f;
            #pragma unroll 8
            for (int i = 0; i < 64; ++i) {
                const float4 v = cr[i];
                const float4 xv = xr[i];
                dot = fmaf(v.x, xv.x, dot);
                dot = fmaf(v.y, xv.y, dot);
                dot = fmaf(v.z, xv.z, dot);
                dot = fmaf(v.w, xv.w, dot);
            }
            const float d = c2[code] - 2.f * dot;
            if (d < bd || (d == bd && code < bk)) { bd = d; bk = code; }
        }
        #pragma unroll
        for (int off = 32; off >= 1; off >>= 1) {
            const float od = __shfl_xor(bd, off);
            const int   ok = __shfl_xor(bk, off);
            if (od < bd || (od == bd && ok < bk)) { bd = od; bk = ok; }
        }
        if (lane == 0) { scan_d[wv] = bd; scan_k[wv] = bk; }
        __syncthreads();
        if (tid == 0) {
            float fd = scan_d[0]; int fk = scan_k[0];
            #pragma unroll
            for (int v = 1; v < 8; ++v) {
                const float od = scan_d[v]; const int ok = scan_k[v];
                if (od < fd || (od == fd && ok < fk)) { fd = od; fk = ok; }
            }
            idx_s[wrow] = fk;
        }
        __syncthreads();
    }

    // indices out (post-rescan)
    if (tid < 64) out[IDX_OFF + bh * 64 + tid] = (float)idx_s[tid];

    // ---- Fused epilogue: quant gather (L2-resident cb), coalesced writes,
    //      loss from LDS-reconstructed x (xh+xl, error ~2^-24).
    {
        const int w = tid & 63;           // row
        const int kblk = wv;              // c-eighth: c in [wv*32, wv*32+32)
        const int m = w & 15, mt = w >> 4;
        const int myidx = idx_s[w];
        const float4* cbrow = (const float4*)(cb + (size_t)myidx * Cd + kblk * 32);
        float lsum = 0.f;
        #pragma unroll
        for (int q = 0; q < 4; ++q) {
            const int e = (kblk * 4 + mt) * 64 + q * 16 + m;
            const half8 hv = Axh[e];
            const half8 lv = Axl[e];
            const float4 qa = cbrow[q * 2];
            const float4 qb = cbrow[q * 2 + 1];
            const float qv[8] = {qa.x, qa.y, qa.z, qa.w, qb.x, qb.y, qb.z, qb.w};
            const int cbase = kblk * 32 + q * 8;
            #pragma unroll
            for (int j = 0; j < 8; ++j) {
                const float xv = (float)hv[j] + (float)lv[j];
                const float dd = qv[j] - xv;
                lsum += dd * dd;
                out[(((size_t)b * Cd + cbase + j) * Hn + h) * Wn + w] = qv[j];
            }
        }
        #pragma unroll
        for (int off = 32; off >= 1; off >>= 1) lsum += __shfl_xor(lsum, off);
        if (lane == 0) red[wv] = lsum;
    }
    __syncthreads();
    if (tid == 0) {
        float s = 0.f;
        #pragma unroll
        for (int i = 0; i < 8; ++i) s += red[i];
        s *= (1.0f / 16777216.0f);
        atomicAdd(out + LOSS_OFF, s);
        atomicAdd(out + LOSS_OFF + 1, s);
    }
}

// ---------------------------------------------------------------------------
extern "C" void kernel_launch(void* const* d_in, const int* in_sizes, int n_in,
                              void* d_out, int out_size, void* d_ws, size_t ws_size,
                              hipStream_t stream) {
    const float* x  = (const float*)d_in[0];   // (16,256,64,64)
    const float* cb = (const float*)d_in[1];   // (1024,256)
    float* out = (float*)d_out;
    char* ws = (char*)d_ws;
    _Float16* cbFh = (_Float16*)(ws + WS_CBFH);
    _Float16* cbFl = (_Float16*)(ws + WS_CBFL);
    float* c2      = (float*)(ws + WS_C2);

    prep<<<512, 512, 0, stream>>>(cb, cbFh, cbFl, c2, out);
    vq_main<<<Bn * Hn, 512, 0, stream>>>(x, cbFh, cbFl, c2, cb, out);
}